// Round 17
// baseline (1760.129 us; speedup 1.0000x reference)
//
#include <hip/hip_runtime.h>
#include <math.h>

#define B_ 32
#define C_ 3
#define IMG_ 224
#define P_ 32
#define G_ 7
#define NPATCH 49
#define E_ 768
#define NH_ 12
#define L_ 12
#define DFF_ 3072
#define MLP_ 2048
#define NC_ 5
#define TOK 62
#define MROWS (B_*TOK)      // 1984
#define FLAT_ (TOK*E_)      // 47616
#define MPAD 2048
#define PMROWS (B_*NPATCH)  // 1568
#define PMPAD 1664          // 13*128
#define HKS 31              // head split-K
#define HKC (FLAT_/HKS)     // 1536

typedef __bf16 bf16x8 __attribute__((ext_vector_type(8)));
typedef float f32x4 __attribute__((ext_vector_type(4)));
typedef float f32x16 __attribute__((ext_vector_type(16)));

__device__ inline unsigned short f2bf(float f) {
    unsigned u = __float_as_uint(f);
    u += 0x7FFF + ((u >> 16) & 1);
    return (unsigned short)(u >> 16);
}

__device__ inline unsigned cvtpk(float lo, float hi) {
    unsigned r;
    asm("v_cvt_pk_bf16_f32 %0, %1, %2" : "=v"(r) : "v"(lo), "v"(hi));
    return r;
}

#define GLDS(gsrc, ldst) __builtin_amdgcn_global_load_lds( \
    (__attribute__((address_space(1))) const void*)(gsrc), \
    (__attribute__((address_space(3))) void*)(ldst), 16, 0, 0)

// ---------------- bf16 MFMA GEMM: 128x64 tile, BK=64, 32x32x16 MFMA ----------------
__global__ __launch_bounds__(256) void gemm_mfma(
    const unsigned short* __restrict__ A, const float* __restrict__ W,
    const float* __restrict__ bias, float* __restrict__ Cf, unsigned short* __restrict__ Cb,
    float* __restrict__ part, int Mc, int Mcp, int N, int K, int KC, int act,
    int Smap, int tstart)
{
    __shared__ unsigned short As[128 * 64];   // 16 KB, linear (GLDS dest)
    __shared__ unsigned short Bs[64 * 72];    // 9 KB, padded stride 72
    int tid = threadIdx.x;
    int m0 = blockIdx.y * 128, n0 = blockIdx.x * 64;
    int z = blockIdx.z;
    int kbeg = z * KC;
    int wid = tid >> 6, lane = tid & 63;
    int wm = wid >> 1, wn = wid & 1;
    int lr32 = lane & 31, lg32 = lane >> 5;
    int sr = tid >> 3, sc = (tid & 7) * 8;                        // LDS dest (linear)
    int scs = (((tid & 7) ^ ((tid >> 3) & 7)) * 8);               // swizzled global source col
    int brow = tid >> 2, bq = (tid & 3) * 16;                     // B staging

    const unsigned short* aptr[4];
    #pragma unroll
    for (int tt = 0; tt < 4; ++tt) {
        int m_r = m0 + sr + tt * 32;
        int grow;
        if (Smap > 0) {
            if (m_r < Mc) { int bb = m_r / Smap; grow = bb * TOK + tstart + (m_r - bb * Smap); }
            else grow = 0;
        } else grow = m_r;
        aptr[tt] = A + (size_t)grow * K + scs;
    }

    f32x16 acc0 = {}, acc1 = {};

    for (int k0 = kbeg; k0 < kbeg + KC; k0 += 64) {
        const float* bsrc = &W[(size_t)(n0 + brow) * K + k0 + bq];
        float4 bv0 = *reinterpret_cast<const float4*>(bsrc);
        float4 bv1 = *reinterpret_cast<const float4*>(bsrc + 4);
        float4 bv2 = *reinterpret_cast<const float4*>(bsrc + 8);
        float4 bv3 = *reinterpret_cast<const float4*>(bsrc + 12);
        #pragma unroll
        for (int tt = 0; tt < 4; ++tt)
            GLDS(aptr[tt] + k0, &As[(sr + tt * 32) * 64 + sc]);
        {
            uint4 u0, u1;
            u0.x = cvtpk(bv0.x, bv0.y); u0.y = cvtpk(bv0.z, bv0.w);
            u0.z = cvtpk(bv1.x, bv1.y); u0.w = cvtpk(bv1.z, bv1.w);
            u1.x = cvtpk(bv2.x, bv2.y); u1.y = cvtpk(bv2.z, bv2.w);
            u1.z = cvtpk(bv3.x, bv3.y); u1.w = cvtpk(bv3.z, bv3.w);
            *reinterpret_cast<uint4*>(&Bs[brow * 72 + bq]) = u0;
            *reinterpret_cast<uint4*>(&Bs[brow * 72 + bq + 8]) = u1;
        }
        __syncthreads();
        #pragma unroll
        for (int ks = 0; ks < 64; ks += 16) {
            bf16x8 bfr = *reinterpret_cast<const bf16x8*>(&Bs[(wn * 32 + lr32) * 72 + ks + lg32 * 8]);
            int ckA = (((ks >> 3) + lg32) ^ (lr32 & 7)) << 3;
            bf16x8 af0 = *reinterpret_cast<const bf16x8*>(&As[(wm * 64 + lr32) * 64 + ckA]);
            bf16x8 af1 = *reinterpret_cast<const bf16x8*>(&As[(wm * 64 + 32 + lr32) * 64 + ckA]);
            acc0 = __builtin_amdgcn_mfma_f32_32x32x16_bf16(af0, bfr, acc0, 0, 0, 0);
            acc1 = __builtin_amdgcn_mfma_f32_32x32x16_bf16(af1, bfr, acc1, 0, 0, 0);
        }
        __syncthreads();
    }

    bool split = (gridDim.z > 1);
    int col = n0 + wn * 32 + lr32;
    float bcol = split ? 0.f : bias[col];
    #pragma unroll
    for (int mt = 0; mt < 2; ++mt) {
        #pragma unroll
        for (int reg = 0; reg < 16; ++reg) {
            int row = m0 + wm * 64 + mt * 32 + (reg & 3) + 8 * (reg >> 2) + 4 * lg32;
            float v = mt ? acc1[reg] : acc0[reg];
            if (split) {
                part[((size_t)z * Mcp + row) * N + col] = v;
            } else if (row < Mc) {
                v += bcol;
                if (act) v = fmaxf(v, 0.f);
                if (Cb) Cb[(size_t)row * N + col] = f2bf(v);
                else    Cf[(size_t)row * N + col] = v;
            }
        }
    }
}

// ---------------- residual(+partials+bias) add + LayerNorm, active rows only ----------------
__global__ __launch_bounds__(256) void add_ln_fused(
    const float* __restrict__ h, const float* __restrict__ part, int nparts,
    const float* __restrict__ gb, const float* __restrict__ s, const float* __restrict__ bb,
    float* __restrict__ outf, unsigned short* __restrict__ outbf,
    const float* __restrict__ ximg, int t0, int span, int S, int tstart, int Mcp)
{
    int blk = blockIdx.x;
    int b = blk / span, tl = blk - b * span;
    int t = t0 + tl;
    int row = b * TOK + t;
    int tid = threadIdx.x;
    if (t < tstart) {
        #pragma unroll
        for (int j = 0; j < 3; ++j) {
            int e = tid + j * 256;
            float v = ximg[b * E_ + e];
            if (outf)  outf[(size_t)row * E_ + e] = v;
            if (outbf) outbf[(size_t)row * E_ + e] = f2bf(v);
        }
        return;
    }
    int crow = b * S + (t - tstart);
    __shared__ float sm[8];
    float v[3];
    #pragma unroll
    for (int j = 0; j < 3; ++j) {
        int e = tid + j * 256;
        float x = h[(size_t)row * E_ + e];
        for (int p = 0; p < nparts; ++p) x += part[((size_t)p * Mcp + crow) * E_ + e];
        if (nparts) x += gb[e];
        v[j] = x;
    }
    float sum = v[0] + v[1] + v[2];
    #pragma unroll
    for (int o = 32; o >= 1; o >>= 1) sum += __shfl_xor(sum, o);
    int wid = tid >> 6, lane = tid & 63;
    if (lane == 0) sm[wid] = sum;
    __syncthreads();
    if (tid == 0) sm[0] = sm[0] + sm[1] + sm[2] + sm[3];
    __syncthreads();
    float mu = sm[0] * (1.0f / E_);
    __syncthreads();
    float sq = 0.f;
    #pragma unroll
    for (int j = 0; j < 3; ++j) { float d = v[j] - mu; sq += d * d; }
    #pragma unroll
    for (int o = 32; o >= 1; o >>= 1) sq += __shfl_xor(sq, o);
    if (lane == 0) sm[wid] = sq;
    __syncthreads();
    if (tid == 0) sm[0] = sm[0] + sm[1] + sm[2] + sm[3];
    __syncthreads();
    float rstd = rsqrtf(sm[0] * (1.0f / E_) + 1e-5f);
    #pragma unroll
    for (int j = 0; j < 3; ++j) {
        int e = tid + j * 256;
        float r = (v[j] - mu) * rstd * s[e] + bb[e];
        if (outf)  outf[(size_t)row * E_ + e] = r;
        if (outbf) outbf[(size_t)row * E_ + e] = f2bf(r);
    }
}

// ---------------- MFMA attention: compact rows (b*S + j), junk rows clamped finite ----------------
__global__ __launch_bounds__(256) void attn_mfma(
    const unsigned short* __restrict__ qkv, unsigned short* __restrict__ obf, int S)
{
    int h = blockIdx.x, b = blockIdx.y;
    int tid = threadIdx.x;
    int wid = tid >> 6, lane = tid & 63;
    int lr = lane & 15, lg = lane >> 4;

    __shared__ unsigned short Qs[64 * 64];
    __shared__ unsigned short Ks[64 * 64];
    __shared__ unsigned short VT[64 * 72];
    __shared__ unsigned short Ps[4][16 * 72];

    const unsigned short* qb_base = qkv + (size_t)h * 64;

    #pragma unroll
    for (int t = 0; t < 2; ++t) {
        int r0 = wid * 16 + t * 8;
        int row = r0 + (lane >> 3);
        int rowg = (row < S) ? (b * S + row) : (b * S);
        int sc = ((lane & 7) ^ (row & 7)) * 8;
        GLDS(qb_base + (size_t)rowg * 2304 + sc,       &Qs[r0 * 64]);
        GLDS(qb_base + (size_t)rowg * 2304 + 768 + sc, &Ks[r0 * 64]);
    }
    #pragma unroll
    for (int it = 0; it < 8; ++it) {
        int pi = it * 256 + tid;
        int k = pi >> 5;
        int kg = (k < S) ? (b * S + k) : (b * S);
        int d0 = (pi & 31) * 2;
        unsigned u = *reinterpret_cast<const unsigned*>(qb_base + (size_t)kg * 2304 + 1536 + d0);
        VT[d0 * 72 + k] = (unsigned short)(u & 0xffff);
        VT[(d0 + 1) * 72 + k] = (unsigned short)(u >> 16);
    }
    __syncthreads();

    f32x4 st[4];
    #pragma unroll
    for (int mt = 0; mt < 4; ++mt) st[mt] = (f32x4){0.f, 0.f, 0.f, 0.f};
    bf16x8 qb[2];
    #pragma unroll
    for (int ks = 0; ks < 2; ++ks) {
        int qrow = wid * 16 + lr;
        int ck = ((ks * 4 + lg) ^ (qrow & 7)) * 8;
        qb[ks] = *reinterpret_cast<const bf16x8*>(&Qs[qrow * 64 + ck]);
    }
    #pragma unroll
    for (int mt = 0; mt < 4; ++mt) {
        #pragma unroll
        for (int ks = 0; ks < 2; ++ks) {
            int krow = mt * 16 + lr;
            int ck = ((ks * 4 + lg) ^ (krow & 7)) * 8;
            bf16x8 kb = *reinterpret_cast<const bf16x8*>(&Ks[krow * 64 + ck]);
            st[mt] = __builtin_amdgcn_mfma_f32_16x16x32_bf16(kb, qb[ks], st[mt], 0, 0, 0);
        }
    }

    float mx = -1e30f;
    #pragma unroll
    for (int mt = 0; mt < 4; ++mt)
        #pragma unroll
        for (int rr = 0; rr < 4; ++rr) {
            int k = mt * 16 + lg * 4 + rr;
            float v = st[mt][rr] * 0.125f;
            v = (k < S) ? v : -1e30f;
            st[mt][rr] = v;
            mx = fmaxf(mx, v);
        }
    mx = fmaxf(mx, __shfl_xor(mx, 16));
    mx = fmaxf(mx, __shfl_xor(mx, 32));
    float sum = 0.f;
    #pragma unroll
    for (int mt = 0; mt < 4; ++mt)
        #pragma unroll
        for (int rr = 0; rr < 4; ++rr) {
            float p = __expf(st[mt][rr] - mx);
            st[mt][rr] = p;
            sum += p;
        }
    sum += __shfl_xor(sum, 16);
    sum += __shfl_xor(sum, 32);
    float inv = 1.0f / sum;

    #pragma unroll
    for (int mt = 0; mt < 4; ++mt) {
        int k0 = mt * 16 + lg * 4;
        unsigned u0 = cvtpk(st[mt][0] * inv, st[mt][1] * inv);
        unsigned u1 = cvtpk(st[mt][2] * inv, st[mt][3] * inv);
        *reinterpret_cast<unsigned*>(&Ps[wid][lr * 72 + k0]) = u0;
        *reinterpret_cast<unsigned*>(&Ps[wid][lr * 72 + k0 + 2]) = u1;
    }
    __syncthreads();

    f32x4 oa[4];
    #pragma unroll
    for (int nt = 0; nt < 4; ++nt) oa[nt] = (f32x4){0.f, 0.f, 0.f, 0.f};
    #pragma unroll
    for (int ks = 0; ks < 2; ++ks) {
        bf16x8 pa = *reinterpret_cast<const bf16x8*>(&Ps[wid][lr * 72 + ks * 32 + lg * 8]);
        #pragma unroll
        for (int nt = 0; nt < 4; ++nt) {
            bf16x8 vb = *reinterpret_cast<const bf16x8*>(&VT[(nt * 16 + lr) * 72 + ks * 32 + lg * 8]);
            oa[nt] = __builtin_amdgcn_mfma_f32_16x16x32_bf16(pa, vb, oa[nt], 0, 0, 0);
        }
    }

    #pragma unroll
    for (int nt = 0; nt < 4; ++nt)
        #pragma unroll
        for (int rr = 0; rr < 4; ++rr) {
            int qs = wid * 16 + lg * 4 + rr;
            if (qs < S)
                obf[((size_t)(b * S + qs)) * E_ + h * 64 + nt * 16 + lr] = f2bf(oa[nt][rr]);
        }
}

// ---------------- backbone: per-b 3-channel mean + ximg row (merged) ----------------
__global__ __launch_bounds__(256) void backbone_kernel(
    const float* __restrict__ x, const float* __restrict__ Wbb,
    const float* __restrict__ bbb, float* __restrict__ ximg)
{
    int b = blockIdx.x;
    int tid = threadIdx.x;
    __shared__ float sm[4];
    __shared__ float cm[3];
    int wid = tid >> 6, lane = tid & 63;
    for (int c = 0; c < 3; ++c) {
        const float* p = x + (size_t)(b * 3 + c) * IMG_ * IMG_;
        float s = 0.f;
        for (int i = tid; i < IMG_ * IMG_; i += 256) s += p[i];
        #pragma unroll
        for (int o = 32; o >= 1; o >>= 1) s += __shfl_xor(s, o);
        if (lane == 0) sm[wid] = s;
        __syncthreads();
        if (tid == 0) cm[c] = (sm[0] + sm[1] + sm[2] + sm[3]) / (float)(IMG_ * IMG_);
        __syncthreads();
    }
    #pragma unroll
    for (int j = 0; j < 3; ++j) {
        int e = tid + j * 256;
        ximg[(size_t)b * E_ + e] = cm[0] * Wbb[e] + cm[1] * Wbb[E_ + e]
                                 + cm[2] * Wbb[2 * E_ + e] + bbb[e];
    }
}

// vectorized x4: 4 consecutive k = same (c,p), q..q+3 contiguous in x
__global__ void im2col_kernel(const float* __restrict__ x, unsigned short* __restrict__ Pm)
{
    int idx = (blockIdx.x * 256 + threadIdx.x) * 4;
    if (idx >= PMROWS * 3072) return;
    int k = idx % 3072;
    int rowp = idx / 3072;
    int n = rowp % NPATCH, b = rowp / NPATCH;
    int i = n / G_, j = n % G_;
    int c = k >> 10;
    int r = k & 1023;
    int p = r >> 5, q = r & 31;
    float4 v = *reinterpret_cast<const float4*>(
        &x[(((size_t)b * C_ + c) * IMG_ + i * P_ + p) * IMG_ + j * P_ + q]);
    ushort4 o;
    o.x = f2bf(v.x); o.y = f2bf(v.y); o.z = f2bf(v.z); o.w = f2bf(v.w);
    *reinterpret_cast<ushort4*>(&Pm[idx]) = o;
}

__global__ void build_h0_kernel(const float* __restrict__ part, const float* __restrict__ bp,
                                const float* __restrict__ cls, const float* __restrict__ pos,
                                float* __restrict__ hbuf, unsigned short* __restrict__ hbf)
{
    int idx = blockIdx.x * 256 + threadIdx.x;
    if (idx >= MROWS * E_) return;
    int e = idx % E_;
    int t = (idx / E_) % TOK;
    int b = idx / (E_ * TOK);
    float v = 0.f;
    if (t >= 12) {
        int sseq = t - 12;
        float base;
        if (sseq == 0) base = cls[e];
        else {
            int prow = b * NPATCH + (sseq - 1);
            base = bp[e];
            #pragma unroll
            for (int s = 0; s < 3; ++s) base += part[((size_t)s * PMPAD + prow) * E_ + e];
        }
        v = base + pos[sseq * E_ + e];
    }
    hbuf[idx] = v;
    hbf[idx] = f2bf(v);
}

// ---------------- head1: MFMA streaming, split-K=31, fp32 W converted in-register ----------------
__global__ __launch_bounds__(256) void head1_mfma(
    const unsigned short* __restrict__ hfb, const float* __restrict__ Wh1,
    float* __restrict__ part)
{
    int tid = threadIdx.x;
    int wid = tid >> 6, lane = tid & 63;
    int lr = lane & 15, lg = lane >> 4;
    int n0 = blockIdx.x * 64 + wid * 16;
    int kc = blockIdx.y;
    f32x4 acc0 = (f32x4){0.f, 0.f, 0.f, 0.f};
    f32x4 acc1 = (f32x4){0.f, 0.f, 0.f, 0.f};
    const float* wrow = Wh1 + (size_t)(n0 + lr) * FLAT_ + (size_t)kc * HKC + lg * 8;
    const unsigned short* a0 = hfb + (size_t)lr * FLAT_ + (size_t)kc * HKC + lg * 8;
    const unsigned short* a1 = hfb + (size_t)(16 + lr) * FLAT_ + (size_t)kc * HKC + lg * 8;
    #pragma unroll 4
    for (int k = 0; k < HKC; k += 32) {
        float4 w0 = *reinterpret_cast<const float4*>(wrow + k);
        float4 w1 = *reinterpret_cast<const float4*>(wrow + k + 4);
        uint4 u;
        u.x = cvtpk(w0.x, w0.y); u.y = cvtpk(w0.z, w0.w);
        u.z = cvtpk(w1.x, w1.y); u.w = cvtpk(w1.z, w1.w);
        bf16x8 bw = __builtin_bit_cast(bf16x8, u);
        bf16x8 af0 = *reinterpret_cast<const bf16x8*>(a0 + k);
        bf16x8 af1 = *reinterpret_cast<const bf16x8*>(a1 + k);
        acc0 = __builtin_amdgcn_mfma_f32_16x16x32_bf16(af0, bw, acc0, 0, 0, 0);
        acc1 = __builtin_amdgcn_mfma_f32_16x16x32_bf16(af1, bw, acc1, 0, 0, 0);
    }
    int n = n0 + lr;
    #pragma unroll
    for (int rr = 0; rr < 4; ++rr) {
        int m = lg * 4 + rr;
        part[((size_t)kc * B_ + m) * MLP_ + n] = acc0[rr];
        part[((size_t)kc * B_ + 16 + m) * MLP_ + n] = acc1[rr];
    }
}

__global__ void head1_fin_kernel(const float* __restrict__ part, const float* __restrict__ bh1,
                                 float* __restrict__ out1)
{
    int idx = blockIdx.x * 256 + threadIdx.x;
    if (idx >= B_ * MLP_) return;
    int n = idx % MLP_, b = idx / MLP_;
    float s = bh1[n];
    for (int kc = 0; kc < HKS; ++kc) s += part[((size_t)kc * B_ + b) * MLP_ + n];
    out1[idx] = 0.5f * s * (1.0f + erff(s * 0.70710678118654752f));
}

__global__ __launch_bounds__(256) void head2_kernel(const float* __restrict__ out1,
                                                    const float* __restrict__ Wh2,
                                                    const float* __restrict__ bh2,
                                                    float* __restrict__ out)
{
    int bc = blockIdx.x;
    int b = bc / NC_, c = bc % NC_;
    float s = 0.f;
    for (int nn = threadIdx.x; nn < MLP_; nn += 256) s += out1[(size_t)b * MLP_ + nn] * Wh2[(size_t)c * MLP_ + nn];
    #pragma unroll
    for (int o = 32; o >= 1; o >>= 1) s += __shfl_xor(s, o);
    __shared__ float sm[4];
    int wid = threadIdx.x >> 6, lane = threadIdx.x & 63;
    if (lane == 0) sm[wid] = s;
    __syncthreads();
    if (threadIdx.x == 0) out[bc] = sm[0] + sm[1] + sm[2] + sm[3] + bh2[c];
}

// ---------------- driver ----------------
extern "C" void kernel_launch(void* const* d_in, const int* in_sizes, int n_in,
                              void* d_out, int out_size, void* d_ws, size_t ws_size,
                              hipStream_t stream)
{
    (void)in_sizes; (void)n_in; (void)out_size; (void)ws_size;
    const float* x    = (const float*)d_in[0];
    const float* Wp   = (const float*)d_in[1];
    const float* bp   = (const float*)d_in[2];
    const float* cls  = (const float*)d_in[3];
    const float* pos  = (const float*)d_in[4];
    const float* Wbb  = (const float*)d_in[5];
    const float* bbb  = (const float*)d_in[6];
    const float* Wqkv = (const float*)d_in[7];
    const float* bqkv = (const float*)d_in[8];
    const float* Wo   = (const float*)d_in[9];
    const float* bo   = (const float*)d_in[10];
    const float* ln1s = (const float*)d_in[11];
    const float* ln1b = (const float*)d_in[12];
    const float* W1   = (const float*)d_in[13];
    const float* b1   = (const float*)d_in[14];
    const float* W2   = (const float*)d_in[15];
    const float* b2   = (const float*)d_in[16];
    const float* ln2s = (const float*)d_in[17];
    const float* ln2b = (const float*)d_in[18];
    const float* lnfs = (const float*)d_in[19];
    const float* lnfb = (const float*)d_in[20];
    const float* Wh1  = (const float*)d_in[21];
    const float* bh1  = (const float*)d_in[22];
    const float* Wh2  = (const float*)d_in[23];
    const float* bh2  = (const float*)d_in[24];
    float* out = (float*)d_out;

    float* ws = (float*)d_ws;
    size_t off = 0;
    float* hbuf   = ws + off; off += (size_t)MROWS * E_;
    float* qslab  = ws + off; off += (size_t)3 * MPAD * E_;        // qkv bf16 / split-K partials / head part
    unsigned short* hbf  = (unsigned short*)(ws + off); off += (size_t)MPAD * E_ / 2;
    unsigned short* obf  = (unsigned short*)(ws + off); off += (size_t)MPAD * E_ / 2;
    unsigned short* ffbf = (unsigned short*)(ws + off); off += (size_t)MPAD * DFF_ / 2;
    unsigned short* hfb  = (unsigned short*)(ws + off); off += (size_t)MROWS * E_ / 2;
    float* ximg  = ws + off; off += B_ * E_;
    float* out1  = ws + off; off += B_ * MLP_;

    float* part = qslab;
    unsigned short* qkvb = (unsigned short*)qslab;
    unsigned short* Pmbf = ffbf;

    // backbone token (merged mean + linear)
    backbone_kernel<<<B_, 256, 0, stream>>>(x, Wbb, bbb, ximg);

    // patch embedding: identity-M (PMPAD), split-K=3
    im2col_kernel<<<(PMROWS * 3072 / 4 + 255) / 256, 256, 0, stream>>>(x, Pmbf);
    gemm_mfma<<<dim3(E_ / 64, PMPAD / 128, 3), 256, 0, stream>>>(
        Pmbf, Wp, nullptr, nullptr, nullptr, part, PMPAD, PMPAD, E_, 3072, 1024, 0, 0, 0);
    build_h0_kernel<<<(MROWS * E_ + 255) / 256, 256, 0, stream>>>(part, bp, cls, pos, hbuf, hbf);

    for (int i = 0; i < L_; ++i) {
        int start = 12 - i;
        int S = TOK - start;
        int Mc = B_ * S;
        int Mcp = ((Mc + 127) / 128) * 128;
        gemm_mfma<<<dim3(2304 / 64, Mcp / 128, 1), 256, 0, stream>>>(
            hbf, Wqkv + (size_t)i * 2304 * E_, bqkv + i * 2304, nullptr, qkvb, nullptr,
            Mc, Mcp, 2304, E_, E_, 0, S, start);
        attn_mfma<<<dim3(NH_, B_), 256, 0, stream>>>(qkvb, obf, S);
        // proj: split-K=3 (KC=256) -> ~504-576 blocks
        gemm_mfma<<<dim3(E_ / 64, Mcp / 128, 3), 256, 0, stream>>>(
            obf, Wo + (size_t)i * E_ * E_, nullptr, nullptr, nullptr, part,
            Mc, Mcp, E_, E_, 256, 0, 0, 0);
        add_ln_fused<<<B_ * S, 256, 0, stream>>>(
            hbuf, part, 3, bo + i * E_, ln1s + i * E_, ln1b + i * E_, hbuf, hbf,
            nullptr, start, S, S, start, Mcp);
        gemm_mfma<<<dim3(DFF_ / 64, Mcp / 128, 1), 256, 0, stream>>>(
            hbf, W1 + (size_t)i * DFF_ * E_, b1 + i * DFF_, nullptr, ffbf, nullptr,
            Mc, Mcp, DFF_, E_, E_, 1, S, start);
        // ffn2: split-K=3 (KC=1024)
        gemm_mfma<<<dim3(E_ / 64, Mcp / 128, 3), 256, 0, stream>>>(
            ffbf, W2 + (size_t)i * E_ * DFF_, nullptr, nullptr, nullptr, part,
            Mc, Mcp, E_, DFF_, 1024, 0, 0, 0);
        add_ln_fused<<<B_ * (S + 1), 256, 0, stream>>>(
            hbuf, part, 3, b2 + i * E_, ln2s + i * E_, ln2b + i * E_, hbuf, hbf,
            ximg, start - 1, S + 1, S, start, Mcp);
    }

    // final LN (bf16 only, all 62 rows) + head
    add_ln_fused<<<MROWS, 256, 0, stream>>>(
        hbuf, nullptr, 0, nullptr, lnfs, lnfb, nullptr, hfb, nullptr, 0, TOK, TOK, 0, 1);
    head1_mfma<<<dim3(MLP_ / 64, HKS), 256, 0, stream>>>(hfb, Wh1, part);
    head1_fin_kernel<<<(B_ * MLP_ + 255) / 256, 256, 0, stream>>>(part, bh1, out1);
    head2_kernel<<<B_ * NC_, 256, 0, stream>>>(out1, Wh2, bh2, out);
}

// Round 18
// 1610.038 us; speedup vs baseline: 1.0932x; 1.0932x over previous
//
#include <hip/hip_runtime.h>
#include <math.h>

#define B_ 32
#define C_ 3
#define IMG_ 224
#define P_ 32
#define G_ 7
#define NPATCH 49
#define E_ 768
#define NH_ 12
#define L_ 12
#define DFF_ 3072
#define MLP_ 2048
#define NC_ 5
#define TOK 62
#define MROWS (B_*TOK)      // 1984
#define FLAT_ (TOK*E_)      // 47616
#define MPAD 2048
#define PMROWS (B_*NPATCH)  // 1568
#define PMPAD 1664          // 13*128
#define HKS 31              // head split-K
#define HKC (FLAT_/HKS)     // 1536

typedef __bf16 bf16x8 __attribute__((ext_vector_type(8)));
typedef float f32x4 __attribute__((ext_vector_type(4)));
typedef float f32x16 __attribute__((ext_vector_type(16)));

__device__ inline unsigned short f2bf(float f) {
    unsigned u = __float_as_uint(f);
    u += 0x7FFF + ((u >> 16) & 1);
    return (unsigned short)(u >> 16);
}

__device__ inline unsigned cvtpk(float lo, float hi) {
    unsigned r;
    asm("v_cvt_pk_bf16_f32 %0, %1, %2" : "=v"(r) : "v"(lo), "v"(hi));
    return r;
}

#define GLDS(gsrc, ldst) __builtin_amdgcn_global_load_lds( \
    (__attribute__((address_space(1))) const void*)(gsrc), \
    (__attribute__((address_space(3))) void*)(ldst), 16, 0, 0)

// ---------------- bf16 MFMA GEMM: 128x64 tile, BK=64, 32x32x16 MFMA ----------------
__global__ __launch_bounds__(256) void gemm_mfma(
    const unsigned short* __restrict__ A, const float* __restrict__ W,
    const float* __restrict__ bias, float* __restrict__ Cf, unsigned short* __restrict__ Cb,
    float* __restrict__ part, int Mc, int Mcp, int N, int K, int KC, int act,
    int Smap, int tstart)
{
    __shared__ unsigned short As[128 * 64];   // 16 KB, linear (GLDS dest)
    __shared__ unsigned short Bs[64 * 72];    // 9 KB, padded stride 72
    int tid = threadIdx.x;
    int m0 = blockIdx.y * 128, n0 = blockIdx.x * 64;
    int z = blockIdx.z;
    int kbeg = z * KC;
    int wid = tid >> 6, lane = tid & 63;
    int wm = wid >> 1, wn = wid & 1;
    int lr32 = lane & 31, lg32 = lane >> 5;
    int sr = tid >> 3, sc = (tid & 7) * 8;                        // LDS dest (linear)
    int scs = (((tid & 7) ^ ((tid >> 3) & 7)) * 8);               // swizzled global source col
    int brow = tid >> 2, bq = (tid & 3) * 16;                     // B staging

    const unsigned short* aptr[4];
    #pragma unroll
    for (int tt = 0; tt < 4; ++tt) {
        int m_r = m0 + sr + tt * 32;
        int grow;
        if (Smap > 0) {
            if (m_r < Mc) { int bb = m_r / Smap; grow = bb * TOK + tstart + (m_r - bb * Smap); }
            else grow = 0;
        } else grow = m_r;
        aptr[tt] = A + (size_t)grow * K + scs;
    }

    f32x16 acc0 = {}, acc1 = {};

    for (int k0 = kbeg; k0 < kbeg + KC; k0 += 64) {
        const float* bsrc = &W[(size_t)(n0 + brow) * K + k0 + bq];
        float4 bv0 = *reinterpret_cast<const float4*>(bsrc);
        float4 bv1 = *reinterpret_cast<const float4*>(bsrc + 4);
        float4 bv2 = *reinterpret_cast<const float4*>(bsrc + 8);
        float4 bv3 = *reinterpret_cast<const float4*>(bsrc + 12);
        #pragma unroll
        for (int tt = 0; tt < 4; ++tt)
            GLDS(aptr[tt] + k0, &As[(sr + tt * 32) * 64 + sc]);
        {
            uint4 u0, u1;
            u0.x = cvtpk(bv0.x, bv0.y); u0.y = cvtpk(bv0.z, bv0.w);
            u0.z = cvtpk(bv1.x, bv1.y); u0.w = cvtpk(bv1.z, bv1.w);
            u1.x = cvtpk(bv2.x, bv2.y); u1.y = cvtpk(bv2.z, bv2.w);
            u1.z = cvtpk(bv3.x, bv3.y); u1.w = cvtpk(bv3.z, bv3.w);
            *reinterpret_cast<uint4*>(&Bs[brow * 72 + bq]) = u0;
            *reinterpret_cast<uint4*>(&Bs[brow * 72 + bq + 8]) = u1;
        }
        __syncthreads();
        #pragma unroll
        for (int ks = 0; ks < 64; ks += 16) {
            bf16x8 bfr = *reinterpret_cast<const bf16x8*>(&Bs[(wn * 32 + lr32) * 72 + ks + lg32 * 8]);
            int ckA = (((ks >> 3) + lg32) ^ (lr32 & 7)) << 3;
            bf16x8 af0 = *reinterpret_cast<const bf16x8*>(&As[(wm * 64 + lr32) * 64 + ckA]);
            bf16x8 af1 = *reinterpret_cast<const bf16x8*>(&As[(wm * 64 + 32 + lr32) * 64 + ckA]);
            acc0 = __builtin_amdgcn_mfma_f32_32x32x16_bf16(af0, bfr, acc0, 0, 0, 0);
            acc1 = __builtin_amdgcn_mfma_f32_32x32x16_bf16(af1, bfr, acc1, 0, 0, 0);
        }
        __syncthreads();
    }

    bool split = (gridDim.z > 1);
    int col = n0 + wn * 32 + lr32;
    float bcol = split ? 0.f : bias[col];
    #pragma unroll
    for (int mt = 0; mt < 2; ++mt) {
        #pragma unroll
        for (int reg = 0; reg < 16; ++reg) {
            int row = m0 + wm * 64 + mt * 32 + (reg & 3) + 8 * (reg >> 2) + 4 * lg32;
            float v = mt ? acc1[reg] : acc0[reg];
            if (split) {
                part[((size_t)z * Mcp + row) * N + col] = v;
            } else if (row < Mc) {
                v += bcol;
                if (act) v = fmaxf(v, 0.f);
                if (Cb) Cb[(size_t)row * N + col] = f2bf(v);
                else    Cf[(size_t)row * N + col] = v;
            }
        }
    }
}

// ---------------- residual(+partials+bias) add + LayerNorm, active rows only ----------------
__global__ __launch_bounds__(256) void add_ln_fused(
    const float* __restrict__ h, const float* __restrict__ part, int nparts,
    const float* __restrict__ gb, const float* __restrict__ s, const float* __restrict__ bb,
    float* __restrict__ outf, unsigned short* __restrict__ outbf,
    const float* __restrict__ ximg, int t0, int span, int S, int tstart, int Mcp)
{
    int blk = blockIdx.x;
    int b = blk / span, tl = blk - b * span;
    int t = t0 + tl;
    int row = b * TOK + t;
    int tid = threadIdx.x;
    if (t < tstart) {
        #pragma unroll
        for (int j = 0; j < 3; ++j) {
            int e = tid + j * 256;
            float v = ximg[b * E_ + e];
            if (outf)  outf[(size_t)row * E_ + e] = v;
            if (outbf) outbf[(size_t)row * E_ + e] = f2bf(v);
        }
        return;
    }
    int crow = b * S + (t - tstart);
    __shared__ float sm[8];
    float v[3];
    #pragma unroll
    for (int j = 0; j < 3; ++j) {
        int e = tid + j * 256;
        float x = h[(size_t)row * E_ + e];
        for (int p = 0; p < nparts; ++p) x += part[((size_t)p * Mcp + crow) * E_ + e];
        if (nparts) x += gb[e];
        v[j] = x;
    }
    float sum = v[0] + v[1] + v[2];
    #pragma unroll
    for (int o = 32; o >= 1; o >>= 1) sum += __shfl_xor(sum, o);
    int wid = tid >> 6, lane = tid & 63;
    if (lane == 0) sm[wid] = sum;
    __syncthreads();
    if (tid == 0) sm[0] = sm[0] + sm[1] + sm[2] + sm[3];
    __syncthreads();
    float mu = sm[0] * (1.0f / E_);
    __syncthreads();
    float sq = 0.f;
    #pragma unroll
    for (int j = 0; j < 3; ++j) { float d = v[j] - mu; sq += d * d; }
    #pragma unroll
    for (int o = 32; o >= 1; o >>= 1) sq += __shfl_xor(sq, o);
    if (lane == 0) sm[wid] = sq;
    __syncthreads();
    if (tid == 0) sm[0] = sm[0] + sm[1] + sm[2] + sm[3];
    __syncthreads();
    float rstd = rsqrtf(sm[0] * (1.0f / E_) + 1e-5f);
    #pragma unroll
    for (int j = 0; j < 3; ++j) {
        int e = tid + j * 256;
        float r = (v[j] - mu) * rstd * s[e] + bb[e];
        if (outf)  outf[(size_t)row * E_ + e] = r;
        if (outbf) outbf[(size_t)row * E_ + e] = f2bf(r);
    }
}

// ---------------- MFMA attention: compact rows (b*S + j), junk rows clamped finite ----------------
__global__ __launch_bounds__(256) void attn_mfma(
    const unsigned short* __restrict__ qkv, unsigned short* __restrict__ obf, int S)
{
    int h = blockIdx.x, b = blockIdx.y;
    int tid = threadIdx.x;
    int wid = tid >> 6, lane = tid & 63;
    int lr = lane & 15, lg = lane >> 4;

    __shared__ unsigned short Qs[64 * 64];
    __shared__ unsigned short Ks[64 * 64];
    __shared__ unsigned short VT[64 * 72];
    __shared__ unsigned short Ps[4][16 * 72];

    const unsigned short* qb_base = qkv + (size_t)h * 64;

    #pragma unroll
    for (int t = 0; t < 2; ++t) {
        int r0 = wid * 16 + t * 8;
        int row = r0 + (lane >> 3);
        int rowg = (row < S) ? (b * S + row) : (b * S);
        int sc = ((lane & 7) ^ (row & 7)) * 8;
        GLDS(qb_base + (size_t)rowg * 2304 + sc,       &Qs[r0 * 64]);
        GLDS(qb_base + (size_t)rowg * 2304 + 768 + sc, &Ks[r0 * 64]);
    }
    #pragma unroll
    for (int it = 0; it < 8; ++it) {
        int pi = it * 256 + tid;
        int k = pi >> 5;
        int kg = (k < S) ? (b * S + k) : (b * S);
        int d0 = (pi & 31) * 2;
        unsigned u = *reinterpret_cast<const unsigned*>(qb_base + (size_t)kg * 2304 + 1536 + d0);
        VT[d0 * 72 + k] = (unsigned short)(u & 0xffff);
        VT[(d0 + 1) * 72 + k] = (unsigned short)(u >> 16);
    }
    __syncthreads();

    f32x4 st[4];
    #pragma unroll
    for (int mt = 0; mt < 4; ++mt) st[mt] = (f32x4){0.f, 0.f, 0.f, 0.f};
    bf16x8 qb[2];
    #pragma unroll
    for (int ks = 0; ks < 2; ++ks) {
        int qrow = wid * 16 + lr;
        int ck = ((ks * 4 + lg) ^ (qrow & 7)) * 8;
        qb[ks] = *reinterpret_cast<const bf16x8*>(&Qs[qrow * 64 + ck]);
    }
    #pragma unroll
    for (int mt = 0; mt < 4; ++mt) {
        #pragma unroll
        for (int ks = 0; ks < 2; ++ks) {
            int krow = mt * 16 + lr;
            int ck = ((ks * 4 + lg) ^ (krow & 7)) * 8;
            bf16x8 kb = *reinterpret_cast<const bf16x8*>(&Ks[krow * 64 + ck]);
            st[mt] = __builtin_amdgcn_mfma_f32_16x16x32_bf16(kb, qb[ks], st[mt], 0, 0, 0);
        }
    }

    float mx = -1e30f;
    #pragma unroll
    for (int mt = 0; mt < 4; ++mt)
        #pragma unroll
        for (int rr = 0; rr < 4; ++rr) {
            int k = mt * 16 + lg * 4 + rr;
            float v = st[mt][rr] * 0.125f;
            v = (k < S) ? v : -1e30f;
            st[mt][rr] = v;
            mx = fmaxf(mx, v);
        }
    mx = fmaxf(mx, __shfl_xor(mx, 16));
    mx = fmaxf(mx, __shfl_xor(mx, 32));
    float sum = 0.f;
    #pragma unroll
    for (int mt = 0; mt < 4; ++mt)
        #pragma unroll
        for (int rr = 0; rr < 4; ++rr) {
            float p = __expf(st[mt][rr] - mx);
            st[mt][rr] = p;
            sum += p;
        }
    sum += __shfl_xor(sum, 16);
    sum += __shfl_xor(sum, 32);
    float inv = 1.0f / sum;

    #pragma unroll
    for (int mt = 0; mt < 4; ++mt) {
        int k0 = mt * 16 + lg * 4;
        unsigned u0 = cvtpk(st[mt][0] * inv, st[mt][1] * inv);
        unsigned u1 = cvtpk(st[mt][2] * inv, st[mt][3] * inv);
        *reinterpret_cast<unsigned*>(&Ps[wid][lr * 72 + k0]) = u0;
        *reinterpret_cast<unsigned*>(&Ps[wid][lr * 72 + k0 + 2]) = u1;
    }
    __syncthreads();

    f32x4 oa[4];
    #pragma unroll
    for (int nt = 0; nt < 4; ++nt) oa[nt] = (f32x4){0.f, 0.f, 0.f, 0.f};
    #pragma unroll
    for (int ks = 0; ks < 2; ++ks) {
        bf16x8 pa = *reinterpret_cast<const bf16x8*>(&Ps[wid][lr * 72 + ks * 32 + lg * 8]);
        #pragma unroll
        for (int nt = 0; nt < 4; ++nt) {
            bf16x8 vb = *reinterpret_cast<const bf16x8*>(&VT[(nt * 16 + lr) * 72 + ks * 32 + lg * 8]);
            oa[nt] = __builtin_amdgcn_mfma_f32_16x16x32_bf16(pa, vb, oa[nt], 0, 0, 0);
        }
    }

    #pragma unroll
    for (int nt = 0; nt < 4; ++nt)
        #pragma unroll
        for (int rr = 0; rr < 4; ++rr) {
            int qs = wid * 16 + lg * 4 + rr;
            if (qs < S)
                obf[((size_t)(b * S + qs)) * E_ + h * 64 + nt * 16 + lr] = f2bf(oa[nt][rr]);
        }
}

// ---------------- small glue kernels ----------------
__global__ __launch_bounds__(256) void mean_kernel(const float* __restrict__ x, float* __restrict__ xmean)
{
    int bc = blockIdx.x;
    const float* p = x + (size_t)bc * IMG_ * IMG_;
    float s = 0.f;
    for (int i = threadIdx.x; i < IMG_ * IMG_; i += 256) s += p[i];
    #pragma unroll
    for (int o = 32; o >= 1; o >>= 1) s += __shfl_xor(s, o);
    __shared__ float sm[4];
    int wid = threadIdx.x >> 6, lane = threadIdx.x & 63;
    if (lane == 0) sm[wid] = s;
    __syncthreads();
    if (threadIdx.x == 0) xmean[bc] = (sm[0] + sm[1] + sm[2] + sm[3]) / (float)(IMG_ * IMG_);
}

__global__ void ximg_kernel(const float* __restrict__ xmean, const float* __restrict__ Wbb,
                            const float* __restrict__ bbb, float* __restrict__ ximg)
{
    int idx = blockIdx.x * 256 + threadIdx.x;
    if (idx >= B_ * E_) return;
    int e = idx % E_, b = idx / E_;
    ximg[idx] = xmean[b * 3 + 0] * Wbb[0 * E_ + e]
              + xmean[b * 3 + 1] * Wbb[1 * E_ + e]
              + xmean[b * 3 + 2] * Wbb[2 * E_ + e] + bbb[e];
}

// vectorized x4: 4 consecutive k = same (c,p), q..q+3 contiguous in x
__global__ void im2col_kernel(const float* __restrict__ x, unsigned short* __restrict__ Pm)
{
    int idx = (blockIdx.x * 256 + threadIdx.x) * 4;
    if (idx >= PMROWS * 3072) return;
    int k = idx % 3072;
    int rowp = idx / 3072;
    int n = rowp % NPATCH, b = rowp / NPATCH;
    int i = n / G_, j = n % G_;
    int c = k >> 10;
    int r = k & 1023;
    int p = r >> 5, q = r & 31;
    float4 v = *reinterpret_cast<const float4*>(
        &x[(((size_t)b * C_ + c) * IMG_ + i * P_ + p) * IMG_ + j * P_ + q]);
    ushort4 o;
    o.x = f2bf(v.x); o.y = f2bf(v.y); o.z = f2bf(v.z); o.w = f2bf(v.w);
    *reinterpret_cast<ushort4*>(&Pm[idx]) = o;
}

__global__ void build_h0_kernel(const float* __restrict__ part, const float* __restrict__ bp,
                                const float* __restrict__ cls, const float* __restrict__ pos,
                                float* __restrict__ hbuf, unsigned short* __restrict__ hbf)
{
    int idx = blockIdx.x * 256 + threadIdx.x;
    if (idx >= MROWS * E_) return;
    int e = idx % E_;
    int t = (idx / E_) % TOK;
    int b = idx / (E_ * TOK);
    float v = 0.f;
    if (t >= 12) {
        int sseq = t - 12;
        float base;
        if (sseq == 0) base = cls[e];
        else {
            int prow = b * NPATCH + (sseq - 1);
            base = bp[e];
            #pragma unroll
            for (int s = 0; s < 3; ++s) base += part[((size_t)s * PMPAD + prow) * E_ + e];
        }
        v = base + pos[sseq * E_ + e];
    }
    hbuf[idx] = v;
    hbf[idx] = f2bf(v);
}

// ---------------- head1: MFMA streaming, split-K=31, fp32 W converted in-register ----------------
__global__ __launch_bounds__(256) void head1_mfma(
    const unsigned short* __restrict__ hfb, const float* __restrict__ Wh1,
    float* __restrict__ part)
{
    int tid = threadIdx.x;
    int wid = tid >> 6, lane = tid & 63;
    int lr = lane & 15, lg = lane >> 4;
    int n0 = blockIdx.x * 64 + wid * 16;
    int kc = blockIdx.y;
    f32x4 acc0 = (f32x4){0.f, 0.f, 0.f, 0.f};
    f32x4 acc1 = (f32x4){0.f, 0.f, 0.f, 0.f};
    const float* wrow = Wh1 + (size_t)(n0 + lr) * FLAT_ + (size_t)kc * HKC + lg * 8;
    const unsigned short* a0 = hfb + (size_t)lr * FLAT_ + (size_t)kc * HKC + lg * 8;
    const unsigned short* a1 = hfb + (size_t)(16 + lr) * FLAT_ + (size_t)kc * HKC + lg * 8;
    #pragma unroll 4
    for (int k = 0; k < HKC; k += 32) {
        float4 w0 = *reinterpret_cast<const float4*>(wrow + k);
        float4 w1 = *reinterpret_cast<const float4*>(wrow + k + 4);
        uint4 u;
        u.x = cvtpk(w0.x, w0.y); u.y = cvtpk(w0.z, w0.w);
        u.z = cvtpk(w1.x, w1.y); u.w = cvtpk(w1.z, w1.w);
        bf16x8 bw = __builtin_bit_cast(bf16x8, u);
        bf16x8 af0 = *reinterpret_cast<const bf16x8*>(a0 + k);
        bf16x8 af1 = *reinterpret_cast<const bf16x8*>(a1 + k);
        acc0 = __builtin_amdgcn_mfma_f32_16x16x32_bf16(af0, bw, acc0, 0, 0, 0);
        acc1 = __builtin_amdgcn_mfma_f32_16x16x32_bf16(af1, bw, acc1, 0, 0, 0);
    }
    int n = n0 + lr;
    #pragma unroll
    for (int rr = 0; rr < 4; ++rr) {
        int m = lg * 4 + rr;
        part[((size_t)kc * B_ + m) * MLP_ + n] = acc0[rr];
        part[((size_t)kc * B_ + 16 + m) * MLP_ + n] = acc1[rr];
    }
}

__global__ void head1_fin_kernel(const float* __restrict__ part, const float* __restrict__ bh1,
                                 float* __restrict__ out1)
{
    int idx = blockIdx.x * 256 + threadIdx.x;
    if (idx >= B_ * MLP_) return;
    int n = idx % MLP_, b = idx / MLP_;
    float s = bh1[n];
    for (int kc = 0; kc < HKS; ++kc) s += part[((size_t)kc * B_ + b) * MLP_ + n];
    out1[idx] = 0.5f * s * (1.0f + erff(s * 0.70710678118654752f));
}

__global__ __launch_bounds__(256) void head2_kernel(const float* __restrict__ out1,
                                                    const float* __restrict__ Wh2,
                                                    const float* __restrict__ bh2,
                                                    float* __restrict__ out)
{
    int bc = blockIdx.x;
    int b = bc / NC_, c = bc % NC_;
    float s = 0.f;
    for (int nn = threadIdx.x; nn < MLP_; nn += 256) s += out1[(size_t)b * MLP_ + nn] * Wh2[(size_t)c * MLP_ + nn];
    #pragma unroll
    for (int o = 32; o >= 1; o >>= 1) s += __shfl_xor(s, o);
    __shared__ float sm[4];
    int wid = threadIdx.x >> 6, lane = threadIdx.x & 63;
    if (lane == 0) sm[wid] = s;
    __syncthreads();
    if (threadIdx.x == 0) out[bc] = sm[0] + sm[1] + sm[2] + sm[3] + bh2[c];
}

// ---------------- driver ----------------
extern "C" void kernel_launch(void* const* d_in, const int* in_sizes, int n_in,
                              void* d_out, int out_size, void* d_ws, size_t ws_size,
                              hipStream_t stream)
{
    (void)in_sizes; (void)n_in; (void)out_size; (void)ws_size;
    const float* x    = (const float*)d_in[0];
    const float* Wp   = (const float*)d_in[1];
    const float* bp   = (const float*)d_in[2];
    const float* cls  = (const float*)d_in[3];
    const float* pos  = (const float*)d_in[4];
    const float* Wbb  = (const float*)d_in[5];
    const float* bbb  = (const float*)d_in[6];
    const float* Wqkv = (const float*)d_in[7];
    const float* bqkv = (const float*)d_in[8];
    const float* Wo   = (const float*)d_in[9];
    const float* bo   = (const float*)d_in[10];
    const float* ln1s = (const float*)d_in[11];
    const float* ln1b = (const float*)d_in[12];
    const float* W1   = (const float*)d_in[13];
    const float* b1   = (const float*)d_in[14];
    const float* W2   = (const float*)d_in[15];
    const float* b2   = (const float*)d_in[16];
    const float* ln2s = (const float*)d_in[17];
    const float* ln2b = (const float*)d_in[18];
    const float* lnfs = (const float*)d_in[19];
    const float* lnfb = (const float*)d_in[20];
    const float* Wh1  = (const float*)d_in[21];
    const float* bh1  = (const float*)d_in[22];
    const float* Wh2  = (const float*)d_in[23];
    const float* bh2  = (const float*)d_in[24];
    float* out = (float*)d_out;

    float* ws = (float*)d_ws;
    size_t off = 0;
    float* hbuf   = ws + off; off += (size_t)MROWS * E_;
    float* qslab  = ws + off; off += (size_t)3 * MPAD * E_;        // qkv bf16 / split-K partials / head part
    unsigned short* hbf  = (unsigned short*)(ws + off); off += (size_t)MPAD * E_ / 2;
    unsigned short* obf  = (unsigned short*)(ws + off); off += (size_t)MPAD * E_ / 2;
    unsigned short* ffbf = (unsigned short*)(ws + off); off += (size_t)MPAD * DFF_ / 2;
    unsigned short* hfb  = (unsigned short*)(ws + off); off += (size_t)MROWS * E_ / 2;
    float* ximg  = ws + off; off += B_ * E_;
    float* xmean = ws + off; off += 128;
    float* out1  = ws + off; off += B_ * MLP_;

    float* part = qslab;
    unsigned short* qkvb = (unsigned short*)qslab;
    unsigned short* Pmbf = ffbf;

    // backbone token (parallel: 96-block mean + ximg)
    mean_kernel<<<B_ * C_, 256, 0, stream>>>(x, xmean);
    ximg_kernel<<<(B_ * E_ + 255) / 256, 256, 0, stream>>>(xmean, Wbb, bbb, ximg);

    // patch embedding: identity-M (PMPAD), split-K=3
    im2col_kernel<<<(PMROWS * 3072 / 4 + 255) / 256, 256, 0, stream>>>(x, Pmbf);
    gemm_mfma<<<dim3(E_ / 64, PMPAD / 128, 3), 256, 0, stream>>>(
        Pmbf, Wp, nullptr, nullptr, nullptr, part, PMPAD, PMPAD, E_, 3072, 1024, 0, 0, 0);
    build_h0_kernel<<<(MROWS * E_ + 255) / 256, 256, 0, stream>>>(part, bp, cls, pos, hbuf, hbf);

    for (int i = 0; i < L_; ++i) {
        int start = 12 - i;
        int S = TOK - start;
        int Mc = B_ * S;
        int Mcp = ((Mc + 127) / 128) * 128;
        gemm_mfma<<<dim3(2304 / 64, Mcp / 128, 1), 256, 0, stream>>>(
            hbf, Wqkv + (size_t)i * 2304 * E_, bqkv + i * 2304, nullptr, qkvb, nullptr,
            Mc, Mcp, 2304, E_, E_, 0, S, start);
        attn_mfma<<<dim3(NH_, B_), 256, 0, stream>>>(qkvb, obf, S);
        // proj: split-K=3 (KC=256)
        gemm_mfma<<<dim3(E_ / 64, Mcp / 128, 3), 256, 0, stream>>>(
            obf, Wo + (size_t)i * E_ * E_, nullptr, nullptr, nullptr, part,
            Mc, Mcp, E_, E_, 256, 0, 0, 0);
        add_ln_fused<<<B_ * S, 256, 0, stream>>>(
            hbuf, part, 3, bo + i * E_, ln1s + i * E_, ln1b + i * E_, hbuf, hbf,
            nullptr, start, S, S, start, Mcp);
        gemm_mfma<<<dim3(DFF_ / 64, Mcp / 128, 1), 256, 0, stream>>>(
            hbf, W1 + (size_t)i * DFF_ * E_, b1 + i * DFF_, nullptr, ffbf, nullptr,
            Mc, Mcp, DFF_, E_, E_, 1, S, start);
        // ffn2: split-K=3 (KC=1024)
        gemm_mfma<<<dim3(E_ / 64, Mcp / 128, 3), 256, 0, stream>>>(
            ffbf, W2 + (size_t)i * E_ * DFF_, nullptr, nullptr, nullptr, part,
            Mc, Mcp, E_, DFF_, 1024, 0, 0, 0);
        add_ln_fused<<<B_ * (S + 1), 256, 0, stream>>>(
            hbuf, part, 3, b2 + i * E_, ln2s + i * E_, ln2b + i * E_, hbuf, hbf,
            ximg, start - 1, S + 1, S, start, Mcp);
    }

    // final LN (bf16 only, all 62 rows) + head
    add_ln_fused<<<MROWS, 256, 0, stream>>>(
        hbuf, nullptr, 0, nullptr, lnfs, lnfb, nullptr, hfb, nullptr, 0, TOK, TOK, 0, 1);
    head1_mfma<<<dim3(MLP_ / 64, HKS), 256, 0, stream>>>(hfb, Wh1, part);
    head1_fin_kernel<<<(B_ * MLP_ + 255) / 256, 256, 0, stream>>>(part, bh1, out1);
    head2_kernel<<<B_ * NC_, 256, 0, stream>>>(out1, Wh2, bh2, out);
}